// Round 4
// baseline (23.231 us; speedup 1.0000x reference)
//
#include <hip/hip_runtime.h>
#include <hip/hip_bf16.h>
#include <stdint.h>
#include <math.h>

// Nucleus sampling reduces to row-wise max+argmax:
// the top-p filter never removes the row max (mask is shifted right by one,
// so the first sorted element always survives; stable argsort preserves
// first-occurrence on ties). So output = (argmax(logits,-1), max(logits,-1)).
//
// Output layout (read back as float32):
//   d_out[0 .. S-1]   = tokens (exact integer values as float)
//   d_out[S .. 2S-1]  = scores (float)
//
// R4: two-phase. Phase 1: each row split into P=4 segments, one 256-thread
// block per segment (2048 blocks, 8 blocks/CU, 32 waves/CU) with 4 independent
// (val,idx) chains -> 4 dwordx4 loads in flight per wave (128 KB/CU
// outstanding). Partials in d_ws. Phase 2: tiny merge kernel.
// Discriminates "scheduling/MLP-bound" (expect ~17-19us) vs "HBM floor +
// fixed replay overhead" (expect ~22us unchanged).

#define P 4
#define T1 256

__global__ __launch_bounds__(T1) void partial_rowmax_kernel(
    const float* __restrict__ logits, float* __restrict__ pval,
    int* __restrict__ pidx, int S, int V, int seg) {
    const int bid = blockIdx.x;
    const int row = bid >> 2;        // P == 4
    const int p   = bid & 3;
    const int start = p * seg;
    int end = start + seg;
    if (end > V) end = V;
    const int n = end - start;

    const float* rp = logits + (size_t)row * (size_t)V + start;

    // Alignment peel to 16B for vector loads.
    int head = (int)(((16u - ((uintptr_t)rp & 15u)) & 15u) >> 2);
    if (head > n) head = n;
    const int nvec = (n - head) >> 2;
    const int tail_start = head + (nvec << 2);
    const int ntail = n - tail_start;

    const int tid = threadIdx.x;

    // Four independent (val, idx) chains: 4 loads in flight per wave, short
    // dependent compare chains. Each chain visits strictly increasing global
    // indices, so strict '>' keeps first occurrence within a chain.
    float b0 = -INFINITY, b1 = -INFINITY, b2 = -INFINITY, b3 = -INFINITY;
    int i0 = 0x7fffffff, i1 = 0x7fffffff, i2 = 0x7fffffff, i3 = 0x7fffffff;

    if (tid < head) { b0 = rp[tid]; i0 = start + tid; }

    const float4* __restrict__ vp = (const float4*)(rp + head);
    const int gbase = start + head;  // global index of vp[0].x
    int i = tid;
    for (; i + 3 * T1 < nvec; i += 4 * T1) {
        const float4 a = vp[i];
        const float4 b = vp[i + T1];
        const float4 c = vp[i + 2 * T1];
        const float4 d = vp[i + 3 * T1];
        const int ka = gbase + (i << 2);
        const int kb = gbase + ((i + T1) << 2);
        const int kc = gbase + ((i + 2 * T1) << 2);
        const int kd = gbase + ((i + 3 * T1) << 2);
        if (a.x > b0) { b0 = a.x; i0 = ka; }
        if (a.y > b0) { b0 = a.y; i0 = ka + 1; }
        if (a.z > b0) { b0 = a.z; i0 = ka + 2; }
        if (a.w > b0) { b0 = a.w; i0 = ka + 3; }
        if (b.x > b1) { b1 = b.x; i1 = kb; }
        if (b.y > b1) { b1 = b.y; i1 = kb + 1; }
        if (b.z > b1) { b1 = b.z; i1 = kb + 2; }
        if (b.w > b1) { b1 = b.w; i1 = kb + 3; }
        if (c.x > b2) { b2 = c.x; i2 = kc; }
        if (c.y > b2) { b2 = c.y; i2 = kc + 1; }
        if (c.z > b2) { b2 = c.z; i2 = kc + 2; }
        if (c.w > b2) { b2 = c.w; i2 = kc + 3; }
        if (d.x > b3) { b3 = d.x; i3 = kd; }
        if (d.y > b3) { b3 = d.y; i3 = kd + 1; }
        if (d.z > b3) { b3 = d.z; i3 = kd + 2; }
        if (d.w > b3) { b3 = d.w; i3 = kd + 3; }
    }
    for (; i < nvec; i += T1) {   // remainder, chain 0 (increasing indices)
        const float4 a = vp[i];
        const int ka = gbase + (i << 2);
        if (a.x > b0) { b0 = a.x; i0 = ka; }
        if (a.y > b0) { b0 = a.y; i0 = ka + 1; }
        if (a.z > b0) { b0 = a.z; i0 = ka + 2; }
        if (a.w > b0) { b0 = a.w; i0 = ka + 3; }
    }
    if (tid < ntail) {            // scalar tail (largest indices)
        const float v = rp[tail_start + tid];
        if (v > b0) { b0 = v; i0 = start + tail_start + tid; }
    }

    // Merge chains: greater val, or equal val with lower global index.
    float best = b0; int bidx = i0;
    if (b1 > best || (b1 == best && i1 < bidx)) { best = b1; bidx = i1; }
    if (b2 > best || (b2 == best && i2 < bidx)) { best = b2; bidx = i2; }
    if (b3 > best || (b3 == best && i3 < bidx)) { best = b3; bidx = i3; }

    // Wave (64-lane) reduction.
    #pragma unroll
    for (int off = 32; off >= 1; off >>= 1) {
        const float ov = __shfl_down(best, off, 64);
        const int   oi = __shfl_down(bidx, off, 64);
        if (ov > best || (ov == best && oi < bidx)) { best = ov; bidx = oi; }
    }

    // Cross-wave reduction via LDS (T1/64 = 4 waves).
    __shared__ float s_val[T1 / 64];
    __shared__ int   s_idx[T1 / 64];
    const int wave = tid >> 6;
    const int lane = tid & 63;
    if (lane == 0) { s_val[wave] = best; s_idx[wave] = bidx; }
    __syncthreads();

    if (tid == 0) {
        float fb = s_val[0];
        int fi = s_idx[0];
        #pragma unroll
        for (int w = 1; w < T1 / 64; ++w) {
            const float ov = s_val[w];
            const int   oi = s_idx[w];
            if (ov > fb || (ov == fb && oi < fi)) { fb = ov; fi = oi; }
        }
        pval[bid] = fb;
        pidx[bid] = fi;
    }
}

__global__ __launch_bounds__(256) void final_merge_kernel(
    const float* __restrict__ pval, const int* __restrict__ pidx,
    float* __restrict__ out, int S) {
    const int r = blockIdx.x * blockDim.x + threadIdx.x;
    if (r >= S) return;
    float best = pval[r * P];
    int bidx = pidx[r * P];
    #pragma unroll
    for (int p = 1; p < P; ++p) {
        const float v = pval[r * P + p];
        const int   ix = pidx[r * P + p];
        if (v > best || (v == best && ix < bidx)) { best = v; bidx = ix; }
    }
    out[r]     = (float)bidx;  // token index, exact as float (< 2^24)
    out[S + r] = best;         // score
}

extern "C" void kernel_launch(void* const* d_in, const int* in_sizes, int n_in,
                              void* d_out, int out_size, void* d_ws, size_t ws_size,
                              hipStream_t stream) {
    const float* logits = (const float*)d_in[0];
    float* out = (float*)d_out;

    const int S = out_size / 2;              // 512 rows
    const int V = in_sizes[0] / S;           // 50257 vocab
    const int seg = (V + P - 1) / P;

    float* pval = (float*)d_ws;
    int*   pidx = (int*)((char*)d_ws + (size_t)S * P * sizeof(float));

    partial_rowmax_kernel<<<S * P, T1, 0, stream>>>(logits, pval, pidx, S, V, seg);
    final_merge_kernel<<<(S + 255) / 256, 256, 0, stream>>>(pval, pidx, out, S);
}

// Round 6
// 20.803 us; speedup vs baseline: 1.1167x; 1.1167x over previous
//
#include <hip/hip_runtime.h>
#include <hip/hip_bf16.h>
#include <stdint.h>
#include <math.h>

// Nucleus sampling reduces to row-wise max+argmax:
// the top-p filter never removes the row max (mask is shifted right by one,
// so the first sorted element always survives; stable argsort preserves
// first-occurrence on ties). So output = (argmax(logits,-1), max(logits,-1)).
//
// Output layout (read back as float32):
//   d_out[0 .. S-1]   = tokens (exact integer values as float)
//   d_out[S .. 2S-1]  = scores (float)
//
// R6 = R5 with compile fix: __builtin_nontemporal_load requires a native
// vector type, not HIP_vector_type. Use ext_vector_type(4) float.
// Single kernel, 512 thr/block, 4 independent (val,idx) chains, nt loads.

#define BLOCK 512

typedef float floatx4 __attribute__((ext_vector_type(4)));

__device__ __forceinline__ floatx4 ntload(const floatx4* __restrict__ p) {
    return __builtin_nontemporal_load(p);
}

__global__ __launch_bounds__(BLOCK) void rowmax_argmax_kernel(
    const float* __restrict__ logits, float* __restrict__ out, int S, int V) {
    const int row = blockIdx.x;
    const float* rp = logits + (size_t)row * (size_t)V;

    // Alignment peel: leading elements until 16B-aligned (V % 4 != 0, so
    // each row has its own phase).
    int head = (int)(((16u - ((uintptr_t)rp & 15u)) & 15u) >> 2);
    if (head > V) head = V;
    const int nvec = (V - head) >> 2;
    const int tail_start = head + (nvec << 2);
    const int ntail = V - tail_start;

    const int tid = threadIdx.x;

    // Four independent (val, idx) chains; each chain visits strictly
    // increasing indices so strict '>' keeps first occurrence per chain.
    float b0 = -INFINITY, b1 = -INFINITY, b2 = -INFINITY, b3 = -INFINITY;
    int i0 = 0x7fffffff, i1 = 0x7fffffff, i2 = 0x7fffffff, i3 = 0x7fffffff;

    if (tid < head) { b0 = rp[tid]; i0 = tid; }

    const floatx4* __restrict__ vp = (const floatx4*)(rp + head);
    int i = tid;
    for (; i + 3 * BLOCK < nvec; i += 4 * BLOCK) {
        const floatx4 a = ntload(vp + i);
        const floatx4 b = ntload(vp + i + BLOCK);
        const floatx4 c = ntload(vp + i + 2 * BLOCK);
        const floatx4 d = ntload(vp + i + 3 * BLOCK);
        const int ka = head + (i << 2);
        const int kb = head + ((i + BLOCK) << 2);
        const int kc = head + ((i + 2 * BLOCK) << 2);
        const int kd = head + ((i + 3 * BLOCK) << 2);
        if (a.x > b0) { b0 = a.x; i0 = ka; }
        if (a.y > b0) { b0 = a.y; i0 = ka + 1; }
        if (a.z > b0) { b0 = a.z; i0 = ka + 2; }
        if (a.w > b0) { b0 = a.w; i0 = ka + 3; }
        if (b.x > b1) { b1 = b.x; i1 = kb; }
        if (b.y > b1) { b1 = b.y; i1 = kb + 1; }
        if (b.z > b1) { b1 = b.z; i1 = kb + 2; }
        if (b.w > b1) { b1 = b.w; i1 = kb + 3; }
        if (c.x > b2) { b2 = c.x; i2 = kc; }
        if (c.y > b2) { b2 = c.y; i2 = kc + 1; }
        if (c.z > b2) { b2 = c.z; i2 = kc + 2; }
        if (c.w > b2) { b2 = c.w; i2 = kc + 3; }
        if (d.x > b3) { b3 = d.x; i3 = kd; }
        if (d.y > b3) { b3 = d.y; i3 = kd + 1; }
        if (d.z > b3) { b3 = d.z; i3 = kd + 2; }
        if (d.w > b3) { b3 = d.w; i3 = kd + 3; }
    }
    for (; i < nvec; i += BLOCK) {   // remainder on chain 0 (increasing idx)
        const floatx4 a = ntload(vp + i);
        const int ka = head + (i << 2);
        if (a.x > b0) { b0 = a.x; i0 = ka; }
        if (a.y > b0) { b0 = a.y; i0 = ka + 1; }
        if (a.z > b0) { b0 = a.z; i0 = ka + 2; }
        if (a.w > b0) { b0 = a.w; i0 = ka + 3; }
    }
    if (tid < ntail) {               // scalar tail (largest indices, last)
        const float v = rp[tail_start + tid];
        if (v > b0) { b0 = v; i0 = tail_start + tid; }
    }

    // Merge chains: greater val, or equal val with lower index.
    float best = b0; int bidx = i0;
    if (b1 > best || (b1 == best && i1 < bidx)) { best = b1; bidx = i1; }
    if (b2 > best || (b2 == best && i2 < bidx)) { best = b2; bidx = i2; }
    if (b3 > best || (b3 == best && i3 < bidx)) { best = b3; bidx = i3; }

    // Wave (64-lane) reduction.
    #pragma unroll
    for (int off = 32; off >= 1; off >>= 1) {
        const float ov = __shfl_down(best, off, 64);
        const int   oi = __shfl_down(bidx, off, 64);
        if (ov > best || (ov == best && oi < bidx)) { best = ov; bidx = oi; }
    }

    // Cross-wave reduction via LDS (BLOCK/64 waves).
    __shared__ float s_val[BLOCK / 64];
    __shared__ int   s_idx[BLOCK / 64];
    const int wave = tid >> 6;
    const int lane = tid & 63;
    if (lane == 0) { s_val[wave] = best; s_idx[wave] = bidx; }
    __syncthreads();

    if (tid == 0) {
        float fb = s_val[0];
        int fi = s_idx[0];
        #pragma unroll
        for (int w = 1; w < BLOCK / 64; ++w) {
            const float ov = s_val[w];
            const int   oi = s_idx[w];
            if (ov > fb || (ov == fb && oi < fi)) { fb = ov; fi = oi; }
        }
        out[row]     = (float)fi;  // token index, exact as float (< 2^24)
        out[S + row] = fb;         // score
    }
}

extern "C" void kernel_launch(void* const* d_in, const int* in_sizes, int n_in,
                              void* d_out, int out_size, void* d_ws, size_t ws_size,
                              hipStream_t stream) {
    const float* logits = (const float*)d_in[0];
    float* out = (float*)d_out;

    const int S = out_size / 2;              // 512 rows
    const int V = in_sizes[0] / S;           // 50257 vocab

    rowmax_argmax_kernel<<<S, BLOCK, 0, stream>>>(logits, out, S, V);
}